// Round 3
// baseline (113.138 us; speedup 1.0000x reference)
//
#include <hip/hip_runtime.h>

#define WINDOW 48
#define RES 50
#define PRED 96
#define SEG 100
#define BATCH 2048
#define KTRUNC 12

// ws layout (floats):
//   M  [RES][WINDOW]   at offset 0      (2400)
//   Dk [16][RES]       at offset 2400   (800)
//   L  [BATCH][RES]    at offset 3200   (102400)

__global__ __launch_bounds__(256) void k0_setup(const float* __restrict__ W_lin,
                                                const float* __restrict__ W_in,
                                                const float* __restrict__ d,
                                                float* __restrict__ ws) {
    float* M  = ws;
    float* Dk = ws + 2400;
    int tid = threadIdx.x;
    // M[r][w] = sum_v W_in[r][v] * W_lin[v][w]; 10 blocks x 240 entries
    int e = blockIdx.x * 240 + tid;
    if (tid < 240 && e < RES * WINDOW) {
        int r = e / WINDOW, w = e % WINDOW;
        float acc = 0.f;
        for (int v = 0; v < WINDOW; ++v)
            acc = fmaf(W_in[r * WINDOW + v], W_lin[v * WINDOW + w], acc);
        M[e] = acc;
    }
    if (blockIdx.x == 0 && tid < RES) {
        float dv = d[tid];
        float d2 = dv * dv;
        float d4 = d2 * d2;
        float d8 = d4 * d4;
        float d16 = d8 * d8;
        float d32 = d16 * d16;
        float d64 = d32 * d32;
        float D = d64 * d32 * d4;   // d^100
        float p = 1.f;
        for (int k = 0; k < 16; ++k) { Dk[k * RES + tid] = p; p *= D; }
    }
}

// One block (320 thr = 5 waves) per batch. Wave w owns windows j = 20w..20w+19.
// Lane l (<50) owns channel r=l: M[r,:] in 48 VGPRs, d_r in a VGPR.
// x rows are wave-uniform -> scalar/broadcast loads, no LDS in the hot loop.
// Horner over j ascending: acc = acc*d + dot48(x_j, M_r), then weight d^(20*(4-w)).
__global__ __launch_bounds__(320) void k1_local(const float* __restrict__ x,
                                                const float* __restrict__ Mg,
                                                const float* __restrict__ d,
                                                float* __restrict__ L) {
    __shared__ float Ps[5][52];
    int b = blockIdx.x;
    int w = threadIdx.x >> 6;          // j-group 0..4
    int l = threadIdx.x & 63;          // lane; r = l for l<50
    int r = (l < 50) ? l : 49;

    float4 Mr[12];
    const float4* mrow = (const float4*)(Mg + r * WINDOW);
#pragma unroll
    for (int q = 0; q < 12; ++q) Mr[q] = mrow[q];

    float dv = d[r];
    float d2 = dv * dv, d4 = d2 * d2, d5 = d4 * dv, d10 = d5 * d5, d20 = d10 * d10;

    const float* xg = x + (size_t)b * (SEG * WINDOW) + w * 20 * WINDOW;

    float acc = 0.f;
    for (int jj = 0; jj < 20; ++jj) {
        // wave-uniform row base -> scalar load / single broadcast fetch
        int off = __builtin_amdgcn_readfirstlane(jj * WINDOW);
        const float* xj = xg + off;
        float dx = 0.f, dy = 0.f, dz = 0.f, dw_ = 0.f;
#pragma unroll
        for (int q = 0; q < 12; ++q) {
            float4 xv = *(const float4*)(xj + 4 * q);
            dx  = fmaf(xv.x, Mr[q].x, dx);
            dy  = fmaf(xv.y, Mr[q].y, dy);
            dz  = fmaf(xv.z, Mr[q].z, dz);
            dw_ = fmaf(xv.w, Mr[q].w, dw_);
        }
        acc = fmaf(acc, dv, (dx + dy) + (dz + dw_));   // Horner, j ascending
    }
    // group weight d^(20*(4-w))
    float gw = 1.f;
    for (int k = w; k < 4; ++k) gw *= d20;
    if (l < 50) Ps[w][l] = acc * gw;
    __syncthreads();

    int t = threadIdx.x;
    if (t < RES) {
        float s = (Ps[0][t] + Ps[1][t]) + (Ps[2][t] + Ps[3][t]) + Ps[4][t];
        L[b * RES + t] = s;
    }
}

// One block per batch: s[r] = sum_k D^k * L[b-k][r]; out[b][o] = s . W_out[o]
__global__ __launch_bounds__(128) void k2_out(const float* __restrict__ L,
                                              const float* __restrict__ Dk,
                                              const float* __restrict__ W_out,
                                              float* __restrict__ out) {
    __shared__ float s_s[RES];
    int b = blockIdx.x;
    int t = threadIdx.x;
    if (t < RES) {
        float acc = 0.f;
#pragma unroll
        for (int k = 0; k < KTRUNC; ++k) {
            int bb = b - k;
            if (bb >= 0) acc = fmaf(Dk[k * RES + t], L[bb * RES + t], acc);
        }
        s_s[t] = acc;
    }
    __syncthreads();
    if (t < PRED) {
        const float* wrow = W_out + t * RES;
        float acc = 0.f;
#pragma unroll
        for (int r = 0; r < RES; ++r) acc = fmaf(s_s[r], wrow[r], acc);
        out[b * PRED + t] = acc;
    }
}

extern "C" void kernel_launch(void* const* d_in, const int* in_sizes, int n_in,
                              void* d_out, int out_size, void* d_ws, size_t ws_size,
                              hipStream_t stream) {
    const float* x     = (const float*)d_in[0];
    const float* W_lin = (const float*)d_in[1];
    const float* W_in  = (const float*)d_in[2];
    const float* d     = (const float*)d_in[3];
    const float* W_out = (const float*)d_in[4];
    float* out = (float*)d_out;
    float* ws  = (float*)d_ws;

    float* M  = ws;
    float* Dk = ws + 2400;
    float* L  = ws + 3200;

    k0_setup<<<10, 256, 0, stream>>>(W_lin, W_in, d, ws);
    k1_local<<<BATCH, 320, 0, stream>>>(x, M, d, L);
    k2_out<<<BATCH, 128, 0, stream>>>(L, Dk, W_out, out);
}

// Round 4
// 46.915 us; speedup vs baseline: 2.4116x; 2.4116x over previous
//
#include <hip/hip_runtime.h>

#define WINDOW 48
#define RES 50
#define PRED 96
#define SEG 100
#define BATCH 2048
#define KTRUNC 12
#define VPAD 101   // LDS stride for Vs: odd -> conflict-free both phases

// ws layout (floats):
//   M  [RES][WINDOW]   at offset 0      (2400)
//   Dk [16][RES]       at offset 2400   (800)
//   L  [BATCH][RES]    at offset 3200   (102400)

__global__ __launch_bounds__(256) void k0_setup(const float* __restrict__ W_lin,
                                                const float* __restrict__ W_in,
                                                const float* __restrict__ d,
                                                float* __restrict__ ws) {
    float* M  = ws;
    float* Dk = ws + 2400;
    int tid = threadIdx.x;
    // M[r][w] = sum_v W_in[r][v] * W_lin[v][w]; 10 blocks x 240 entries
    int e = blockIdx.x * 240 + tid;
    if (tid < 240 && e < RES * WINDOW) {
        int r = e / WINDOW, w = e % WINDOW;
        float acc = 0.f;
        for (int v = 0; v < WINDOW; ++v)
            acc = fmaf(W_in[r * WINDOW + v], W_lin[v * WINDOW + w], acc);
        M[e] = acc;
    }
    if (blockIdx.x == 0 && tid < RES) {
        float dv = d[tid];
        float d2 = dv * dv;
        float d4 = d2 * d2;
        float d8 = d4 * d4;
        float d16 = d8 * d8;
        float d32 = d16 * d16;
        float d64 = d32 * d32;
        float D = d64 * d32 * d4;   // d^100
        float p = 1.f;
        for (int k = 0; k < 16; ++k) { Dk[k * RES + tid] = p; p *= D; }
    }
}

// One block (128 thr) per batch b. Lane j (<100) owns window j:
//   x[b,j,:] in 48 VGPRs (12 coalesced-enough dwordx4; bytes exact via L2).
//   Channel loop: M[c,:] read at thread-uniform address -> s_load (SGPRs,
//   scalar pipe), FMAs are v_fmac v,s,v. dot -> Vs[c][j] (LDS transpose).
// Phase 2: lane r (<50) does the exact Horner over j from Vs[r][:].
__global__ __launch_bounds__(128) void k1_local(const float* __restrict__ x,
                                                const float* __restrict__ Mg,
                                                const float* __restrict__ d,
                                                float* __restrict__ L) {
    __shared__ float Vs[RES * VPAD];   // 20.2 KB
    int b = blockIdx.x;
    int j = threadIdx.x;

    if (j < SEG) {
        float2 xr[24];
        const float2* xp = (const float2*)(x + (size_t)b * (SEG * WINDOW) + j * WINDOW);
#pragma unroll
        for (int q = 0; q < 24; ++q) xr[q] = xp[q];

#pragma unroll 2
        for (int c = 0; c < RES; ++c) {
            const float2* mp = (const float2*)(Mg + c * WINDOW);  // uniform -> s_load
            float2 a0 = {0.f, 0.f}, a1 = {0.f, 0.f}, a2 = {0.f, 0.f}, a3 = {0.f, 0.f};
#pragma unroll
            for (int q = 0; q < 24; q += 4) {
                float2 m0 = mp[q], m1 = mp[q + 1], m2 = mp[q + 2], m3 = mp[q + 3];
                a0.x = fmaf(xr[q].x,     m0.x, a0.x);
                a0.y = fmaf(xr[q].y,     m0.y, a0.y);
                a1.x = fmaf(xr[q + 1].x, m1.x, a1.x);
                a1.y = fmaf(xr[q + 1].y, m1.y, a1.y);
                a2.x = fmaf(xr[q + 2].x, m2.x, a2.x);
                a2.y = fmaf(xr[q + 2].y, m2.y, a2.y);
                a3.x = fmaf(xr[q + 3].x, m3.x, a3.x);
                a3.y = fmaf(xr[q + 3].y, m3.y, a3.y);
            }
            float dot = ((a0.x + a0.y) + (a1.x + a1.y))
                      + ((a2.x + a2.y) + (a3.x + a3.y));
            Vs[c * VPAD + j] = dot;
        }
    }
    __syncthreads();

    int t = threadIdx.x;
    if (t < RES) {
        float dv = d[t];
        float s = 0.f;
        const float* vrow = Vs + t * VPAD;
#pragma unroll 4
        for (int jj = 0; jj < SEG; ++jj)
            s = fmaf(s, dv, vrow[jj]);      // s = sum_j d^(99-j) v_j
        L[b * RES + t] = s;
    }
}

// One block per batch: s[r] = sum_k D^k * L[b-k][r]; out[b][o] = s . W_out[o]
__global__ __launch_bounds__(128) void k2_out(const float* __restrict__ L,
                                              const float* __restrict__ Dk,
                                              const float* __restrict__ W_out,
                                              float* __restrict__ out) {
    __shared__ float s_s[RES];
    int b = blockIdx.x;
    int t = threadIdx.x;
    if (t < RES) {
        float acc = 0.f;
#pragma unroll
        for (int k = 0; k < KTRUNC; ++k) {
            int bb = b - k;
            if (bb >= 0) acc = fmaf(Dk[k * RES + t], L[bb * RES + t], acc);
        }
        s_s[t] = acc;
    }
    __syncthreads();
    if (t < PRED) {
        const float* wrow = W_out + t * RES;
        float acc = 0.f;
#pragma unroll
        for (int r = 0; r < RES; ++r) acc = fmaf(s_s[r], wrow[r], acc);
        out[b * PRED + t] = acc;
    }
}

extern "C" void kernel_launch(void* const* d_in, const int* in_sizes, int n_in,
                              void* d_out, int out_size, void* d_ws, size_t ws_size,
                              hipStream_t stream) {
    const float* x     = (const float*)d_in[0];
    const float* W_lin = (const float*)d_in[1];
    const float* W_in  = (const float*)d_in[2];
    const float* d     = (const float*)d_in[3];
    const float* W_out = (const float*)d_in[4];
    float* out = (float*)d_out;
    float* ws  = (float*)d_ws;

    float* M  = ws;
    float* Dk = ws + 2400;
    float* L  = ws + 3200;

    k0_setup<<<10, 256, 0, stream>>>(W_lin, W_in, d, ws);
    k1_local<<<BATCH, 128, 0, stream>>>(x, M, d, L);
    k2_out<<<BATCH, 128, 0, stream>>>(L, Dk, W_out, out);
}